// Round 11
// baseline (5616.641 us; speedup 1.0000x reference)
//
#include <hip/hip_runtime.h>
#include <hip/hip_bf16.h>
#include <cmath>

// Problem constants
#define N_   128
#define T_   64
#define D_   1024
#define H_   1024
#define G4_  4096   // 4*H

typedef short bf16x8 __attribute__((ext_vector_type(8)));
typedef float f32x4  __attribute__((ext_vector_type(4)));

__device__ __forceinline__ unsigned short f2bf(float f) {
    union { float f; unsigned int u; } v; v.f = f;
    unsigned int r = (v.u + 0x7FFFu + ((v.u >> 16) & 1u)) >> 16;  // RNE
    return (unsigned short)r;
}
__device__ __forceinline__ float bf2f(unsigned short s) {
    union { unsigned int u; float f; } v; v.u = ((unsigned int)s) << 16;
    return v.f;
}

// Fragment-packed layout (mfma_f32_16x16x32_bf16, lane = kg*16+cl):
//   P[tile][kc][lane][8] bf16 ; wave fragment load = base + lane*8 -> 1KB contiguous.

// ---------------------------------------------------------------- prep ----

__global__ void k_zero(int* __restrict__ p) { p[threadIdx.x] = 0; }

// pack weight src f32 [1024][4096] (k-major) -> fragment-packed B (rows = j).
__global__ void k_pack_w(const float* __restrict__ src, unsigned short* __restrict__ dst,
                         int kcoff, int kctot) {
    __shared__ float ld[64][33];
    int j0 = blockIdx.x * 32, k0 = blockIdx.y * 64;
    int tid = threadIdx.x;
    int c = tid & 31, r = tid >> 5;           // 32 j x 8 k
    #pragma unroll
    for (int i = 0; i < 8; i++)
        ld[r + i * 8][c] = src[(long)(k0 + r + i * 8) * G4_ + j0 + c];
    __syncthreads();
    int j = tid & 31, ku = tid >> 5;          // 32 j x 8 k-units of 8
    int kcl = ku >> 2, kg = ku & 3;
    int jti = (j0 + j) >> 4, cl = (j0 + j) & 15;
    int kc = kcoff + (k0 >> 5) + kcl;
    unsigned short q[8];
    #pragma unroll
    for (int e = 0; e < 8; e++) q[e] = f2bf(ld[ku * 8 + e][j]);
    *(uint4*)(dst + ((long)(jti * kctot + kc) * 64 + kg * 16 + cl) * 8) = *(uint4*)q;
}

// pack x f32 [N][T][D] -> xP tiles over m: tile = t*8 + (n>>4), rows = n&15.
__global__ void k_pack_x2(const float* __restrict__ x, unsigned short* __restrict__ xP) {
    long gid = (long)blockIdx.x * 256 + threadIdx.x;   // 8192*128
    int m = (int)(gid >> 7), u = (int)(gid & 127);
    const float* src = x + (long)m * 1024 + u * 8;
    int n = m >> 6, t = m & 63;
    int tile = t * 8 + (n >> 4);
    int kc = u >> 2, kg = u & 3, cl = n & 15;
    float4 a = *(const float4*)src, b = *(const float4*)(src + 4);
    unsigned short q[8] = {f2bf(a.x), f2bf(a.y), f2bf(a.z), f2bf(a.w),
                           f2bf(b.x), f2bf(b.y), f2bf(b.z), f2bf(b.w)};
    *(uint4*)(xP + ((long)(tile * 32 + kc) * 64 + kg * 16 + cl) * 8) = *(uint4*)q;
}

// A f32 [N][H][16] -> AfP (A-operand tiles: tile=n, row=p, k=h) + Af2 bf16 copy.
__global__ void k_pack_af(const float* __restrict__ A, unsigned short* __restrict__ AfP,
                          unsigned short* __restrict__ Af2) {
    __shared__ float ld[64][17];
    int n = blockIdx.x, h0 = blockIdx.y * 64;
    int tid = threadIdx.x;
    int hh = tid >> 2, pq = tid & 3;
    float4 v = *(const float4*)(A + ((long)n * H_ + h0 + hh) * 16 + pq * 4);
    unsigned short o[4] = {f2bf(v.x), f2bf(v.y), f2bf(v.z), f2bf(v.w)};
    *(uint2*)(Af2 + ((long)n * H_ + h0 + hh) * 16 + pq * 4) = *(uint2*)o;
    ld[hh][pq * 4 + 0] = v.x; ld[hh][pq * 4 + 1] = v.y;
    ld[hh][pq * 4 + 2] = v.z; ld[hh][pq * 4 + 3] = v.w;
    __syncthreads();
    if (tid < 128) {
        int p = tid >> 3, ku = tid & 7;
        int kc = (h0 >> 5) + (ku >> 2), kg = ku & 3;
        unsigned short q[8];
        #pragma unroll
        for (int e = 0; e < 8; e++) q[e] = f2bf(ld[ku * 8 + e][p]);
        *(uint4*)(AfP + ((long)(n * 32 + kc) * 64 + kg * 16 + p) * 8) = *(uint4*)q;
    }
}

// h0 = mean_p A; c0 = h0; packed h0.
__global__ void k_h0(const float* __restrict__ A, float* __restrict__ h,
                     float* __restrict__ c, unsigned short* __restrict__ hP0) {
    long id = (long)blockIdx.x * 256 + threadIdx.x;
    const float4* ap = (const float4*)(A + id * 16);
    float s = 0.f;
    #pragma unroll
    for (int q = 0; q < 4; q++) { float4 v = ap[q]; s += v.x + v.y + v.z + v.w; }
    float m = s * (1.0f / 16.0f);
    h[id] = m; c[id] = m;
    int n = (int)(id >> 10), j = (int)(id & 1023);
    hP0[((long)((n >> 4) * 32 + (j >> 5)) * 64 + ((j >> 3) & 3) * 16 + (n & 15)) * 8 + (j & 7)] = f2bf(m);
}

// t=0 score partials
__global__ __launch_bounds__(512)
void k_part0(const float* __restrict__ hbuf, const unsigned short* __restrict__ Af2,
             float* __restrict__ partial0) {
    int n = blockIdx.x;
    int tid = threadIdx.x;
    int jh = tid * 2;
    float sp[16];
    #pragma unroll
    for (int p = 0; p < 16; p++) sp[p] = 0.f;
    #pragma unroll
    for (int u = 0; u < 2; u++) {
        float hv = hbuf[(long)n * H_ + jh + u];
        const unsigned short* afp = Af2 + ((long)n * H_ + jh + u) * 16;
        bf16x8 a0 = *(const bf16x8*)(afp);
        bf16x8 a1 = *(const bf16x8*)(afp + 8);
        #pragma unroll
        for (int p = 0; p < 8; p++) { sp[p] += hv * bf2f((unsigned short)a0[p]);
                                      sp[8+p] += hv * bf2f((unsigned short)a1[p]); }
    }
    #pragma unroll
    for (int off = 1; off < 8; off <<= 1) {
        #pragma unroll
        for (int p = 0; p < 16; p++) sp[p] += __shfl_xor(sp[p], off);
    }
    int jt = tid >> 3;
    if ((tid & 7) == 0) {
        #pragma unroll
        for (int p = 0; p < 16; p++)
            partial0[((long)n * 16 + p) * 64 + jt] = sp[p];
    }
}

// prep-only: reduce partial -> softmax -> w0
__global__ __launch_bounds__(64)
void k_score_tiny(const float* __restrict__ partial, float* __restrict__ wbuf) {
    int n = blockIdx.x;
    int lane = threadIdx.x;
    int p = lane & 15, c4 = lane >> 4;
    const float* src = partial + ((long)n * 16 + p) * 64 + c4 * 16;
    float s = 0.f;
    #pragma unroll
    for (int q = 0; q < 16; q++) s += src[q];
    s += __shfl_xor(s, 16);
    s += __shfl_xor(s, 32);
    s *= (1.0f / 32.0f);
    float m = s;
    #pragma unroll
    for (int off = 1; off < 16; off <<= 1) m = fmaxf(m, __shfl_xor(m, off));
    float e = expf(s - m);
    float sum = e;
    #pragma unroll
    for (int off = 1; off < 16; off <<= 1) sum += __shfl_xor(sum, off);
    if (c4 == 0) wbuf[n * 16 + p] = e / sum;
}

// AW = AfP @ WattnP^T (R10-proven, untouched)
__global__ __launch_bounds__(256, 2)
void k_aw(const unsigned short* __restrict__ AfP, const unsigned short* __restrict__ WattnP,
          unsigned short* __restrict__ AW) {
    int tid = threadIdx.x;
    int wv = tid >> 6, lane = tid & 63;
    int wr = wv >> 1, wc = wv & 1;
    int cl = lane & 15, kg = lane >> 4;
    int at0 = blockIdx.x * 8 + wr * 4;
    int jt0 = blockIdx.y * 8 + wc * 4;

    f32x4 acc[4][4];
    #pragma unroll
    for (int i = 0; i < 4; i++)
        #pragma unroll
        for (int j = 0; j < 4; j++) acc[i][j] = (f32x4){0.f, 0.f, 0.f, 0.f};

    const unsigned short* apx[4];
    const unsigned short* bpx[4];
    #pragma unroll
    for (int i = 0; i < 4; i++) {
        apx[i] = AfP    + (long)(at0 + i) * (32 * 512) + lane * 8;
        bpx[i] = WattnP + (long)(jt0 + i) * (32 * 512) + lane * 8;
    }
    #pragma unroll 2
    for (int kc = 0; kc < 32; kc++) {
        bf16x8 a[4], b[4];
        #pragma unroll
        for (int i = 0; i < 4; i++) a[i] = *(const bf16x8*)(apx[i] + kc * 512);
        #pragma unroll
        for (int i = 0; i < 4; i++) b[i] = *(const bf16x8*)(bpx[i] + kc * 512);
        #pragma unroll
        for (int i = 0; i < 4; i++)
            #pragma unroll
            for (int j = 0; j < 4; j++)
                acc[i][j] = __builtin_amdgcn_mfma_f32_16x16x32_bf16(a[i], b[j], acc[i][j], 0, 0, 0);
    }
    #pragma unroll
    for (int i = 0; i < 4; i++) {
        int n = at0 + i;
        #pragma unroll
        for (int j = 0; j < 4; j++) {
            int jj = (jt0 + j) * 16 + cl;
            #pragma unroll
            for (int v = 0; v < 4; v++) {
                int p = kg * 4 + v;
                AW[((long)n * G4_ + jj) * 16 + p] = f2bf(acc[i][j][v]);
            }
        }
    }
}

// ------------------------------------------------------------- per step ----

// ONE kernel per step. grid (64 jt, 8 nt), 256 thr = 4 K-quarter waves.
// GEMM (PF=2 reg double-buffer, 1KB contiguous loads) -> LDS K-reduce ->
// epilogue (w.AW + b, gates, c/h/out, score partials) ->
// atomic-tail: 64th jt-block per nt reduces partials -> softmax -> w(t+1).
__global__ __launch_bounds__(256, 2)
void k_step(const unsigned short* __restrict__ xP,
            const unsigned short* __restrict__ hPin,
            unsigned short* __restrict__ hPout,
            const unsigned short* __restrict__ WxhP,    // [256 jti][64 kc][512]
            const unsigned short* __restrict__ AW,      // [N][4096][16]
            const unsigned short* __restrict__ Af2,     // [N][H][16]
            const float* __restrict__ wIN,              // [N][16]  (w for step t)
            float* __restrict__ wOUT,                   // [N][16]  (w for step t+1)
            float* __restrict__ partial,                // [N][16][64]
            int* __restrict__ cnt,                      // [64][8]
            const float* __restrict__ bvec,
            float* __restrict__ c,
            float* __restrict__ out, int t) {
    int tid = threadIdx.x;
    int ks = tid >> 6, lane = tid & 63;
    int cl = lane & 15, kg = lane >> 4;
    int jt = blockIdx.x;
    int nt = blockIdx.y;
    int colbase = jt * 16, rowbase = nt * 16;

    // ---- GEMM: PF=2 register double-buffered chunk stream ----
    f32x4 acc[4];
    #pragma unroll
    for (int g = 0; g < 4; g++) acc[g] = (f32x4){0.f, 0.f, 0.f, 0.f};

    const unsigned short* abase = (ks < 2)
        ? xP   + ((long)(t * 8 + nt) * 32 + ks * 16) * 512 + lane * 8
        : hPin + ((long)nt * 32 + (ks - 2) * 16) * 512 + lane * 8;
    const unsigned short* bb[4];
    #pragma unroll
    for (int g = 0; g < 4; g++)
        bb[g] = WxhP + ((long)(g * 64 + jt) * 64 + ks * 16) * 512 + lane * 8;

    bf16x8 aA, bA[4], aB, bB[4];
    aA = *(const bf16x8*)(abase);
    #pragma unroll
    for (int g = 0; g < 4; g++) bA[g] = *(const bf16x8*)(bb[g]);
    aB = *(const bf16x8*)(abase + 512);
    #pragma unroll
    for (int g = 0; g < 4; g++) bB[g] = *(const bf16x8*)(bb[g] + 512);

    #pragma unroll
    for (int i = 0; i < 16; i += 2) {
        #pragma unroll
        for (int g = 0; g < 4; g++)
            acc[g] = __builtin_amdgcn_mfma_f32_16x16x32_bf16(aA, bA[g], acc[g], 0, 0, 0);
        if (i + 2 < 16) {
            aA = *(const bf16x8*)(abase + (i + 2) * 512);
            #pragma unroll
            for (int g = 0; g < 4; g++) bA[g] = *(const bf16x8*)(bb[g] + (i + 2) * 512);
        }
        #pragma unroll
        for (int g = 0; g < 4; g++)
            acc[g] = __builtin_amdgcn_mfma_f32_16x16x32_bf16(aB, bB[g], acc[g], 0, 0, 0);
        if (i + 3 < 16) {
            aB = *(const bf16x8*)(abase + (i + 3) * 512);
            #pragma unroll
            for (int g = 0; g < 4; g++) bB[g] = *(const bf16x8*)(bb[g] + (i + 3) * 512);
        }
    }

    // ---- 4-way K reduce ----
    __shared__ float red[3][64][17];
    __shared__ float act[4][16][17];
    if (ks != 0) {
        #pragma unroll
        for (int g = 0; g < 4; g++)
            #pragma unroll
            for (int v = 0; v < 4; v++) red[ks - 1][lane][g * 4 + v] = acc[g][v];
    }
    __syncthreads();
    if (ks == 0) {
        #pragma unroll
        for (int g = 0; g < 4; g++)
            #pragma unroll
            for (int v = 0; v < 4; v++) {
                float s = acc[g][v] + red[0][lane][g*4+v] + red[1][lane][g*4+v] + red[2][lane][g*4+v];
                act[g][kg * 4 + v][cl] = s;   // C/D row = 4*kg + v
            }
    }
    __syncthreads();

    // ---- epilogue: 256 thr x 1 (n, jh) cell ----
    int nloc = tid >> 4, jl = tid & 15;
    int n = rowbase + nloc, jh = colbase + jl;
    float wv16[16];
    #pragma unroll
    for (int p = 0; p < 16; p++) wv16[p] = wIN[n * 16 + p];

    float s4[4];
    #pragma unroll
    for (int g = 0; g < 4; g++) {
        int j = g * 1024 + jh;
        const unsigned short* awp = AW + ((long)n * G4_ + j) * 16;
        bf16x8 aw0 = *(const bf16x8*)(awp);
        bf16x8 aw1 = *(const bf16x8*)(awp + 8);
        float at = 0.f;
        #pragma unroll
        for (int p = 0; p < 8; p++) at += wv16[p]     * bf2f((unsigned short)aw0[p]);
        #pragma unroll
        for (int p = 0; p < 8; p++) at += wv16[8 + p] * bf2f((unsigned short)aw1[p]);
        s4[g] = act[g][nloc][jl] + at + bvec[j];
    }
    float ig = 1.f / (1.f + expf(-s4[0]));
    float fg = 1.f / (1.f + expf(-s4[1]));
    float og = 1.f / (1.f + expf(-s4[2]));
    float gg = tanhf(s4[3]);
    long idx = (long)n * H_ + jh;
    float cn = fg * c[idx] + ig * gg;
    float hn = og * tanhf(cn);
    c[idx] = cn;
    out[((long)n * T_ + t) * H_ + jh] = hn;
    hPout[((long)((n >> 4) * 32 + (jh >> 5)) * 64 + ((jh >> 3) & 3) * 16 + (n & 15)) * 8 + (jh & 7)] = f2bf(hn);

    // score partials for t+1
    const unsigned short* afp = Af2 + ((long)n * H_ + jh) * 16;
    bf16x8 af0 = *(const bf16x8*)(afp);
    bf16x8 af1 = *(const bf16x8*)(afp + 8);
    float sp[16];
    #pragma unroll
    for (int p = 0; p < 8; p++) { sp[p]     = hn * bf2f((unsigned short)af0[p]);
                                  sp[8 + p] = hn * bf2f((unsigned short)af1[p]); }
    #pragma unroll
    for (int off = 1; off < 16; off <<= 1) {
        #pragma unroll
        for (int p = 0; p < 16; p++) sp[p] += __shfl_xor(sp[p], off);
    }
    float outv = 0.f;
    #pragma unroll
    for (int p = 0; p < 16; p++) if (jl == p) outv = sp[p];
    partial[((long)n * 16 + jl) * 64 + jt] = outv;

    // ---- atomic tail: last jt-block per nt computes softmax w(t+1) ----
    __shared__ int isLast;
    __threadfence();
    __syncthreads();
    if (tid == 0) {
        int ticket = atomicAdd(&cnt[t * 8 + nt], 1);
        isLast = (ticket == 63);
    }
    __syncthreads();
    if (isLast) {
        __threadfence();
        int nl = tid >> 4, p = tid & 15;     // 16 n x 16 p
        int nn = rowbase + nl;
        const float* src = partial + ((long)nn * 16 + p) * 64;
        float s = 0.f;
        #pragma unroll 8
        for (int q = 0; q < 64; q++) s += src[q];
        s *= (1.0f / 32.0f);                 // /sqrt(H)
        float m = s;
        #pragma unroll
        for (int off = 1; off < 16; off <<= 1) m = fmaxf(m, __shfl_xor(m, off));
        float e = expf(s - m);
        float sum = e;
        #pragma unroll
        for (int off = 1; off < 16; off <<= 1) sum += __shfl_xor(sum, off);
        wOUT[nn * 16 + p] = e / sum;
    }
}

// ---------------------------------------------------------------- launch ----

extern "C" void kernel_launch(void* const* d_in, const int* in_sizes, int n_in,
                              void* d_out, int out_size, void* d_ws, size_t ws_size,
                              hipStream_t stream) {
    const float* x     = (const float*)d_in[0];
    const float* A     = (const float*)d_in[1];
    const float* Wx    = (const float*)d_in[2];
    const float* Wh    = (const float*)d_in[3];
    const float* Wattn = (const float*)d_in[4];
    const float* b     = (const float*)d_in[5];
    float* out = (float*)d_out;

    char* ws = (char*)d_ws;
    size_t off = 0;
    auto alloc = [&](size_t bytes) -> void* {
        void* p = ws + off;
        off += (bytes + 255) & ~(size_t)255;
        return p;
    };
    unsigned short* xP     = (unsigned short*)alloc((size_t)512 * 32 * 512 * 2);
    unsigned short* WxhP   = (unsigned short*)alloc((size_t)256 * 64 * 512 * 2);
    unsigned short* WattnP = (unsigned short*)alloc((size_t)256 * 32 * 512 * 2);
    unsigned short* AfP    = (unsigned short*)alloc((size_t)128 * 32 * 512 * 2);
    unsigned short* Af2    = (unsigned short*)alloc((size_t)N_ * H_ * 16 * 2);
    unsigned short* AW     = (unsigned short*)alloc((size_t)N_ * G4_ * 16 * 2);
    float*          hbuf   = (float*)alloc((size_t)N_ * H_ * 4);
    float*          cbuf   = (float*)alloc((size_t)N_ * H_ * 4);
    unsigned short* hP0    = (unsigned short*)alloc((size_t)8 * 32 * 512 * 2);
    unsigned short* hP1    = (unsigned short*)alloc((size_t)8 * 32 * 512 * 2);
    float*          part   = (float*)alloc((size_t)N_ * 16 * 64 * 4);
    float*          wbuf0  = (float*)alloc((size_t)N_ * 16 * 4);
    float*          wbuf1  = (float*)alloc((size_t)N_ * 16 * 4);
    int*            cnt    = (int*)alloc((size_t)64 * 8 * 4);

    // prep
    k_zero<<<dim3(1), dim3(512), 0, stream>>>(cnt);
    k_pack_w<<<dim3(128, 16), dim3(256), 0, stream>>>(Wx,    WxhP,   0,  64);
    k_pack_w<<<dim3(128, 16), dim3(256), 0, stream>>>(Wh,    WxhP,   32, 64);
    k_pack_w<<<dim3(128, 16), dim3(256), 0, stream>>>(Wattn, WattnP, 0,  32);
    k_pack_x2<<<dim3(4096), dim3(256), 0, stream>>>(x, xP);
    k_pack_af<<<dim3(128, 16), dim3(256), 0, stream>>>(A, AfP, Af2);
    k_h0<<<dim3(512), dim3(256), 0, stream>>>(A, hbuf, cbuf, hP0);
    k_part0<<<dim3(N_), dim3(512), 0, stream>>>(hbuf, Af2, part);
    k_score_tiny<<<dim3(N_), dim3(64), 0, stream>>>(part, wbuf0);
    k_aw<<<dim3(16, 32), dim3(256), 0, stream>>>(AfP, WattnP, AW);

    // recurrence: ONE kernel per step
    for (int t = 0; t < T_; t++) {
        unsigned short* hin  = (t & 1) ? hP1 : hP0;
        unsigned short* hout = (t & 1) ? hP0 : hP1;
        float* wIN  = (t & 1) ? wbuf1 : wbuf0;
        float* wOUT = (t & 1) ? wbuf0 : wbuf1;
        k_step<<<dim3(64, 8), dim3(256), 0, stream>>>(xP, hin, hout, WxhP, AW, Af2,
                                                      wIN, wOUT, part, cnt, b, cbuf, out, t);
    }
}

// Round 12
// 1141.586 us; speedup vs baseline: 4.9200x; 4.9200x over previous
//
#include <hip/hip_runtime.h>
#include <hip/hip_bf16.h>
#include <cmath>

// Problem constants
#define N_   128
#define T_   64
#define D_   1024
#define H_   1024
#define G4_  4096   // 4*H

typedef short bf16x8 __attribute__((ext_vector_type(8)));
typedef float f32x4  __attribute__((ext_vector_type(4)));

__device__ __forceinline__ unsigned short f2bf(float f) {
    union { float f; unsigned int u; } v; v.f = f;
    unsigned int r = (v.u + 0x7FFFu + ((v.u >> 16) & 1u)) >> 16;  // RNE
    return (unsigned short)r;
}
__device__ __forceinline__ float bf2f(unsigned short s) {
    union { unsigned int u; float f; } v; v.u = ((unsigned int)s) << 16;
    return v.f;
}

// Fragment-packed layout (mfma_f32_16x16x32_bf16, lane = kg*16+cl):
//   P[tile][kc][lane][8] bf16 ; wave fragment load = base + lane*8 -> 1KB contiguous.

// ---------------------------------------------------------------- prep ----

// pack weight src f32 [1024][4096] (k-major) -> fragment-packed B (rows = j).
__global__ void k_pack_w(const float* __restrict__ src, unsigned short* __restrict__ dst,
                         int kcoff, int kctot) {
    __shared__ float ld[64][33];
    int j0 = blockIdx.x * 32, k0 = blockIdx.y * 64;
    int tid = threadIdx.x;
    int c = tid & 31, r = tid >> 5;           // 32 j x 8 k
    #pragma unroll
    for (int i = 0; i < 8; i++)
        ld[r + i * 8][c] = src[(long)(k0 + r + i * 8) * G4_ + j0 + c];
    __syncthreads();
    int j = tid & 31, ku = tid >> 5;          // 32 j x 8 k-units of 8
    int kcl = ku >> 2, kg = ku & 3;
    int jti = (j0 + j) >> 4, cl = (j0 + j) & 15;
    int kc = kcoff + (k0 >> 5) + kcl;
    unsigned short q[8];
    #pragma unroll
    for (int e = 0; e < 8; e++) q[e] = f2bf(ld[ku * 8 + e][j]);
    *(uint4*)(dst + ((long)(jti * kctot + kc) * 64 + kg * 16 + cl) * 8) = *(uint4*)q;
}

// pack x f32 [N][T][D] -> xP tiles over m: tile = t*8 + (n>>4), rows = n&15.
__global__ void k_pack_x2(const float* __restrict__ x, unsigned short* __restrict__ xP) {
    long gid = (long)blockIdx.x * 256 + threadIdx.x;   // 8192*128
    int m = (int)(gid >> 7), u = (int)(gid & 127);
    const float* src = x + (long)m * 1024 + u * 8;
    int n = m >> 6, t = m & 63;
    int tile = t * 8 + (n >> 4);
    int kc = u >> 2, kg = u & 3, cl = n & 15;
    float4 a = *(const float4*)src, b = *(const float4*)(src + 4);
    unsigned short q[8] = {f2bf(a.x), f2bf(a.y), f2bf(a.z), f2bf(a.w),
                           f2bf(b.x), f2bf(b.y), f2bf(b.z), f2bf(b.w)};
    *(uint4*)(xP + ((long)(tile * 32 + kc) * 64 + kg * 16 + cl) * 8) = *(uint4*)q;
}

// A f32 [N][H][16] -> AfP (A-operand tiles: tile=n, row=p, k=h) + Af2 bf16 copy.
__global__ void k_pack_af(const float* __restrict__ A, unsigned short* __restrict__ AfP,
                          unsigned short* __restrict__ Af2) {
    __shared__ float ld[64][17];
    int n = blockIdx.x, h0 = blockIdx.y * 64;
    int tid = threadIdx.x;
    int hh = tid >> 2, pq = tid & 3;
    float4 v = *(const float4*)(A + ((long)n * H_ + h0 + hh) * 16 + pq * 4);
    unsigned short o[4] = {f2bf(v.x), f2bf(v.y), f2bf(v.z), f2bf(v.w)};
    *(uint2*)(Af2 + ((long)n * H_ + h0 + hh) * 16 + pq * 4) = *(uint2*)o;
    ld[hh][pq * 4 + 0] = v.x; ld[hh][pq * 4 + 1] = v.y;
    ld[hh][pq * 4 + 2] = v.z; ld[hh][pq * 4 + 3] = v.w;
    __syncthreads();
    if (tid < 128) {
        int p = tid >> 3, ku = tid & 7;
        int kc = (h0 >> 5) + (ku >> 2), kg = ku & 3;
        unsigned short q[8];
        #pragma unroll
        for (int e = 0; e < 8; e++) q[e] = f2bf(ld[ku * 8 + e][p]);
        *(uint4*)(AfP + ((long)(n * 32 + kc) * 64 + kg * 16 + p) * 8) = *(uint4*)q;
    }
}

// h0 = mean_p A; c0 = h0; packed h0.
__global__ void k_h0(const float* __restrict__ A, float* __restrict__ h,
                     float* __restrict__ c, unsigned short* __restrict__ hP0) {
    long id = (long)blockIdx.x * 256 + threadIdx.x;
    const float4* ap = (const float4*)(A + id * 16);
    float s = 0.f;
    #pragma unroll
    for (int q = 0; q < 4; q++) { float4 v = ap[q]; s += v.x + v.y + v.z + v.w; }
    float m = s * (1.0f / 16.0f);
    h[id] = m; c[id] = m;
    int n = (int)(id >> 10), j = (int)(id & 1023);
    hP0[((long)((n >> 4) * 32 + (j >> 5)) * 64 + ((j >> 3) & 3) * 16 + (n & 15)) * 8 + (j & 7)] = f2bf(m);
}

// t=0 score partials
__global__ __launch_bounds__(512)
void k_part0(const float* __restrict__ hbuf, const unsigned short* __restrict__ Af2,
             float* __restrict__ partial0) {
    int n = blockIdx.x;
    int tid = threadIdx.x;
    int jh = tid * 2;
    float sp[16];
    #pragma unroll
    for (int p = 0; p < 16; p++) sp[p] = 0.f;
    #pragma unroll
    for (int u = 0; u < 2; u++) {
        float hv = hbuf[(long)n * H_ + jh + u];
        const unsigned short* afp = Af2 + ((long)n * H_ + jh + u) * 16;
        bf16x8 a0 = *(const bf16x8*)(afp);
        bf16x8 a1 = *(const bf16x8*)(afp + 8);
        #pragma unroll
        for (int p = 0; p < 8; p++) { sp[p] += hv * bf2f((unsigned short)a0[p]);
                                      sp[8+p] += hv * bf2f((unsigned short)a1[p]); }
    }
    #pragma unroll
    for (int off = 1; off < 8; off <<= 1) {
        #pragma unroll
        for (int p = 0; p < 16; p++) sp[p] += __shfl_xor(sp[p], off);
    }
    int jt = tid >> 3;
    if ((tid & 7) == 0) {
        #pragma unroll
        for (int p = 0; p < 16; p++)
            partial0[((long)n * 16 + p) * 64 + jt] = sp[p];
    }
}

// reduce partial -> softmax -> w  (per-step, proven R10)
__global__ __launch_bounds__(64)
void k_score_tiny(const float* __restrict__ partial, float* __restrict__ wbuf) {
    int n = blockIdx.x;
    int lane = threadIdx.x;
    int p = lane & 15, c4 = lane >> 4;
    const float* src = partial + ((long)n * 16 + p) * 64 + c4 * 16;
    float s = 0.f;
    #pragma unroll
    for (int q = 0; q < 16; q++) s += src[q];
    s += __shfl_xor(s, 16);
    s += __shfl_xor(s, 32);
    s *= (1.0f / 32.0f);
    float m = s;
    #pragma unroll
    for (int off = 1; off < 16; off <<= 1) m = fmaxf(m, __shfl_xor(m, off));
    float e = expf(s - m);
    float sum = e;
    #pragma unroll
    for (int off = 1; off < 16; off <<= 1) sum += __shfl_xor(sum, off);
    if (c4 == 0) wbuf[n * 16 + p] = e / sum;
}

// AW = AfP @ WattnP^T (R10-proven, untouched)
__global__ __launch_bounds__(256, 2)
void k_aw(const unsigned short* __restrict__ AfP, const unsigned short* __restrict__ WattnP,
          unsigned short* __restrict__ AW) {
    int tid = threadIdx.x;
    int wv = tid >> 6, lane = tid & 63;
    int wr = wv >> 1, wc = wv & 1;
    int cl = lane & 15, kg = lane >> 4;
    int at0 = blockIdx.x * 8 + wr * 4;
    int jt0 = blockIdx.y * 8 + wc * 4;

    f32x4 acc[4][4];
    #pragma unroll
    for (int i = 0; i < 4; i++)
        #pragma unroll
        for (int j = 0; j < 4; j++) acc[i][j] = (f32x4){0.f, 0.f, 0.f, 0.f};

    const unsigned short* apx[4];
    const unsigned short* bpx[4];
    #pragma unroll
    for (int i = 0; i < 4; i++) {
        apx[i] = AfP    + (long)(at0 + i) * (32 * 512) + lane * 8;
        bpx[i] = WattnP + (long)(jt0 + i) * (32 * 512) + lane * 8;
    }
    #pragma unroll 2
    for (int kc = 0; kc < 32; kc++) {
        bf16x8 a[4], b[4];
        #pragma unroll
        for (int i = 0; i < 4; i++) a[i] = *(const bf16x8*)(apx[i] + kc * 512);
        #pragma unroll
        for (int i = 0; i < 4; i++) b[i] = *(const bf16x8*)(bpx[i] + kc * 512);
        #pragma unroll
        for (int i = 0; i < 4; i++)
            #pragma unroll
            for (int j = 0; j < 4; j++)
                acc[i][j] = __builtin_amdgcn_mfma_f32_16x16x32_bf16(a[i], b[j], acc[i][j], 0, 0, 0);
    }
    #pragma unroll
    for (int i = 0; i < 4; i++) {
        int n = at0 + i;
        #pragma unroll
        for (int j = 0; j < 4; j++) {
            int jj = (jt0 + j) * 16 + cl;
            #pragma unroll
            for (int v = 0; v < 4; v++) {
                int p = kg * 4 + v;
                AW[((long)n * G4_ + jj) * 16 + p] = f2bf(acc[i][j][v]);
            }
        }
    }
}

// ------------------------------------------------------------- per step ----

// k_step (R10 structure + PF=2 register double-buffer; NO atomics/fences).
// grid (64 jt, 8 nt), 256 thr = 4 K-quarter waves; 1KB contiguous fragment loads.
__global__ __launch_bounds__(256, 2)
void k_step(const unsigned short* __restrict__ xP,
            const unsigned short* __restrict__ hPin,
            unsigned short* __restrict__ hPout,
            const unsigned short* __restrict__ WxhP,    // [256 jti][64 kc][512]
            const unsigned short* __restrict__ AW,      // [N][4096][16]
            const unsigned short* __restrict__ Af2,     // [N][H][16]
            const float* __restrict__ wbuf,             // [N][16]
            const float* __restrict__ bvec,
            float* __restrict__ c,
            float* __restrict__ partOUT,                // [N][16][64]
            float* __restrict__ out, int t) {
    int tid = threadIdx.x;
    int ks = tid >> 6, lane = tid & 63;
    int cl = lane & 15, kg = lane >> 4;
    int jt = blockIdx.x;
    int nt = blockIdx.y;
    int colbase = jt * 16, rowbase = nt * 16;

    // ---- GEMM: PF=2 register double-buffered chunk stream ----
    f32x4 acc[4];
    #pragma unroll
    for (int g = 0; g < 4; g++) acc[g] = (f32x4){0.f, 0.f, 0.f, 0.f};

    const unsigned short* abase = (ks < 2)
        ? xP   + ((long)(t * 8 + nt) * 32 + ks * 16) * 512 + lane * 8
        : hPin + ((long)nt * 32 + (ks - 2) * 16) * 512 + lane * 8;
    const unsigned short* bb[4];
    #pragma unroll
    for (int g = 0; g < 4; g++)
        bb[g] = WxhP + ((long)(g * 64 + jt) * 64 + ks * 16) * 512 + lane * 8;

    bf16x8 aA, bA[4], aB, bB[4];
    aA = *(const bf16x8*)(abase);
    #pragma unroll
    for (int g = 0; g < 4; g++) bA[g] = *(const bf16x8*)(bb[g]);
    aB = *(const bf16x8*)(abase + 512);
    #pragma unroll
    for (int g = 0; g < 4; g++) bB[g] = *(const bf16x8*)(bb[g] + 512);

    #pragma unroll
    for (int i = 0; i < 16; i += 2) {
        #pragma unroll
        for (int g = 0; g < 4; g++)
            acc[g] = __builtin_amdgcn_mfma_f32_16x16x32_bf16(aA, bA[g], acc[g], 0, 0, 0);
        if (i + 2 < 16) {
            aA = *(const bf16x8*)(abase + (i + 2) * 512);
            #pragma unroll
            for (int g = 0; g < 4; g++) bA[g] = *(const bf16x8*)(bb[g] + (i + 2) * 512);
        }
        #pragma unroll
        for (int g = 0; g < 4; g++)
            acc[g] = __builtin_amdgcn_mfma_f32_16x16x32_bf16(aB, bB[g], acc[g], 0, 0, 0);
        if (i + 3 < 16) {
            aB = *(const bf16x8*)(abase + (i + 3) * 512);
            #pragma unroll
            for (int g = 0; g < 4; g++) bB[g] = *(const bf16x8*)(bb[g] + (i + 3) * 512);
        }
    }

    // ---- 4-way K reduce ----
    __shared__ float red[3][64][17];
    __shared__ float act[4][16][17];
    if (ks != 0) {
        #pragma unroll
        for (int g = 0; g < 4; g++)
            #pragma unroll
            for (int v = 0; v < 4; v++) red[ks - 1][lane][g * 4 + v] = acc[g][v];
    }
    __syncthreads();
    if (ks == 0) {
        #pragma unroll
        for (int g = 0; g < 4; g++)
            #pragma unroll
            for (int v = 0; v < 4; v++) {
                float s = acc[g][v] + red[0][lane][g*4+v] + red[1][lane][g*4+v] + red[2][lane][g*4+v];
                act[g][kg * 4 + v][cl] = s;   // C/D row = 4*kg + v
            }
    }
    __syncthreads();

    // ---- epilogue: 256 thr x 1 (n, jh) cell ----
    int nloc = tid >> 4, jl = tid & 15;
    int n = rowbase + nloc, jh = colbase + jl;
    float wv16[16];
    #pragma unroll
    for (int p = 0; p < 16; p++) wv16[p] = wbuf[n * 16 + p];

    float s4[4];
    #pragma unroll
    for (int g = 0; g < 4; g++) {
        int j = g * 1024 + jh;
        const unsigned short* awp = AW + ((long)n * G4_ + j) * 16;
        bf16x8 aw0 = *(const bf16x8*)(awp);
        bf16x8 aw1 = *(const bf16x8*)(awp + 8);
        float at = 0.f;
        #pragma unroll
        for (int p = 0; p < 8; p++) at += wv16[p]     * bf2f((unsigned short)aw0[p]);
        #pragma unroll
        for (int p = 0; p < 8; p++) at += wv16[8 + p] * bf2f((unsigned short)aw1[p]);
        s4[g] = act[g][nloc][jl] + at + bvec[j];
    }
    float ig = 1.f / (1.f + expf(-s4[0]));
    float fg = 1.f / (1.f + expf(-s4[1]));
    float og = 1.f / (1.f + expf(-s4[2]));
    float gg = tanhf(s4[3]);
    long idx = (long)n * H_ + jh;
    float cn = fg * c[idx] + ig * gg;
    float hn = og * tanhf(cn);
    c[idx] = cn;
    out[((long)n * T_ + t) * H_ + jh] = hn;
    hPout[((long)((n >> 4) * 32 + (jh >> 5)) * 64 + ((jh >> 3) & 3) * 16 + (n & 15)) * 8 + (jh & 7)] = f2bf(hn);

    // score partials for t+1
    const unsigned short* afp = Af2 + ((long)n * H_ + jh) * 16;
    bf16x8 af0 = *(const bf16x8*)(afp);
    bf16x8 af1 = *(const bf16x8*)(afp + 8);
    float sp[16];
    #pragma unroll
    for (int p = 0; p < 8; p++) { sp[p]     = hn * bf2f((unsigned short)af0[p]);
                                  sp[8 + p] = hn * bf2f((unsigned short)af1[p]); }
    #pragma unroll
    for (int off = 1; off < 16; off <<= 1) {
        #pragma unroll
        for (int p = 0; p < 16; p++) sp[p] += __shfl_xor(sp[p], off);
    }
    float outv = 0.f;
    #pragma unroll
    for (int p = 0; p < 16; p++) if (jl == p) outv = sp[p];
    partOUT[((long)n * 16 + jl) * 64 + jt] = outv;
}

// ---------------------------------------------------------------- launch ----

extern "C" void kernel_launch(void* const* d_in, const int* in_sizes, int n_in,
                              void* d_out, int out_size, void* d_ws, size_t ws_size,
                              hipStream_t stream) {
    const float* x     = (const float*)d_in[0];
    const float* A     = (const float*)d_in[1];
    const float* Wx    = (const float*)d_in[2];
    const float* Wh    = (const float*)d_in[3];
    const float* Wattn = (const float*)d_in[4];
    const float* b     = (const float*)d_in[5];
    float* out = (float*)d_out;

    char* ws = (char*)d_ws;
    size_t off = 0;
    auto alloc = [&](size_t bytes) -> void* {
        void* p = ws + off;
        off += (bytes + 255) & ~(size_t)255;
        return p;
    };
    unsigned short* xP     = (unsigned short*)alloc((size_t)512 * 32 * 512 * 2);
    unsigned short* WxhP   = (unsigned short*)alloc((size_t)256 * 64 * 512 * 2);
    unsigned short* WattnP = (unsigned short*)alloc((size_t)256 * 32 * 512 * 2);
    unsigned short* AfP    = (unsigned short*)alloc((size_t)128 * 32 * 512 * 2);
    unsigned short* Af2    = (unsigned short*)alloc((size_t)N_ * H_ * 16 * 2);
    unsigned short* AW     = (unsigned short*)alloc((size_t)N_ * G4_ * 16 * 2);
    float*          hbuf   = (float*)alloc((size_t)N_ * H_ * 4);
    float*          cbuf   = (float*)alloc((size_t)N_ * H_ * 4);
    unsigned short* hP0    = (unsigned short*)alloc((size_t)8 * 32 * 512 * 2);
    unsigned short* hP1    = (unsigned short*)alloc((size_t)8 * 32 * 512 * 2);
    float*          part0  = (float*)alloc((size_t)N_ * 16 * 64 * 4);
    float*          part1  = (float*)alloc((size_t)N_ * 16 * 64 * 4);
    float*          wbuf   = (float*)alloc((size_t)N_ * 16 * 4);

    // prep
    k_pack_w<<<dim3(128, 16), dim3(256), 0, stream>>>(Wx,    WxhP,   0,  64);
    k_pack_w<<<dim3(128, 16), dim3(256), 0, stream>>>(Wh,    WxhP,   32, 64);
    k_pack_w<<<dim3(128, 16), dim3(256), 0, stream>>>(Wattn, WattnP, 0,  32);
    k_pack_x2<<<dim3(4096), dim3(256), 0, stream>>>(x, xP);
    k_pack_af<<<dim3(128, 16), dim3(256), 0, stream>>>(A, AfP, Af2);
    k_h0<<<dim3(512), dim3(256), 0, stream>>>(A, hbuf, cbuf, hP0);
    k_part0<<<dim3(N_), dim3(512), 0, stream>>>(hbuf, Af2, part0);
    k_aw<<<dim3(16, 32), dim3(256), 0, stream>>>(AfP, WattnP, AW);

    // recurrence
    for (int t = 0; t < T_; t++) {
        unsigned short* hin  = (t & 1) ? hP1 : hP0;
        unsigned short* hout = (t & 1) ? hP0 : hP1;
        float* pIN  = (t & 1) ? part1 : part0;
        float* pOUT = (t & 1) ? part0 : part1;
        k_score_tiny<<<dim3(N_), dim3(64), 0, stream>>>(pIN, wbuf);
        k_step<<<dim3(64, 8), dim3(256), 0, stream>>>(xP, hin, hout, WxhP, AW, Af2,
                                                      wbuf, b, cbuf, pOUT, out, t);
    }
}

// Round 13
// 1044.339 us; speedup vs baseline: 5.3782x; 1.0931x over previous
//
#include <hip/hip_runtime.h>
#include <hip/hip_bf16.h>
#include <cmath>

// Problem constants
#define N_   128
#define T_   64
#define D_   1024
#define H_   1024
#define G4_  4096   // 4*H

typedef short bf16x8 __attribute__((ext_vector_type(8)));
typedef float f32x4  __attribute__((ext_vector_type(4)));

__device__ __forceinline__ unsigned short f2bf(float f) {
    union { float f; unsigned int u; } v; v.f = f;
    unsigned int r = (v.u + 0x7FFFu + ((v.u >> 16) & 1u)) >> 16;  // RNE
    return (unsigned short)r;
}
__device__ __forceinline__ float bf2f(unsigned short s) {
    union { unsigned int u; float f; } v; v.u = ((unsigned int)s) << 16;
    return v.f;
}

// Fragment-packed layout (mfma_f32_16x16x32_bf16, lane = kg*16+cl):
//   P[tile][kc][lane][8] bf16 ; wave fragment load = base + lane*8 -> 1KB contiguous.

// ---------------------------------------------------------------- prep ----

// pack weight src f32 [1024][4096] (k-major) -> fragment-packed B (rows = j).
__global__ void k_pack_w(const float* __restrict__ src, unsigned short* __restrict__ dst,
                         int kcoff, int kctot) {
    __shared__ float ld[64][33];
    int j0 = blockIdx.x * 32, k0 = blockIdx.y * 64;
    int tid = threadIdx.x;
    int c = tid & 31, r = tid >> 5;           // 32 j x 8 k
    #pragma unroll
    for (int i = 0; i < 8; i++)
        ld[r + i * 8][c] = src[(long)(k0 + r + i * 8) * G4_ + j0 + c];
    __syncthreads();
    int j = tid & 31, ku = tid >> 5;          // 32 j x 8 k-units of 8
    int kcl = ku >> 2, kg = ku & 3;
    int jti = (j0 + j) >> 4, cl = (j0 + j) & 15;
    int kc = kcoff + (k0 >> 5) + kcl;
    unsigned short q[8];
    #pragma unroll
    for (int e = 0; e < 8; e++) q[e] = f2bf(ld[ku * 8 + e][j]);
    *(uint4*)(dst + ((long)(jti * kctot + kc) * 64 + kg * 16 + cl) * 8) = *(uint4*)q;
}

// pack x f32 [N][T][D] -> xP tiles over m: tile = t*8 + (n>>4), rows = n&15.
__global__ void k_pack_x2(const float* __restrict__ x, unsigned short* __restrict__ xP) {
    long gid = (long)blockIdx.x * 256 + threadIdx.x;   // 8192*128
    int m = (int)(gid >> 7), u = (int)(gid & 127);
    const float* src = x + (long)m * 1024 + u * 8;
    int n = m >> 6, t = m & 63;
    int tile = t * 8 + (n >> 4);
    int kc = u >> 2, kg = u & 3, cl = n & 15;
    float4 a = *(const float4*)src, b = *(const float4*)(src + 4);
    unsigned short q[8] = {f2bf(a.x), f2bf(a.y), f2bf(a.z), f2bf(a.w),
                           f2bf(b.x), f2bf(b.y), f2bf(b.z), f2bf(b.w)};
    *(uint4*)(xP + ((long)(tile * 32 + kc) * 64 + kg * 16 + cl) * 8) = *(uint4*)q;
}

// A f32 [N][H][16] -> AfP (A-operand tiles: tile=n, row=p, k=h) + Af2 bf16 copy.
__global__ void k_pack_af(const float* __restrict__ A, unsigned short* __restrict__ AfP,
                          unsigned short* __restrict__ Af2) {
    __shared__ float ld[64][17];
    int n = blockIdx.x, h0 = blockIdx.y * 64;
    int tid = threadIdx.x;
    int hh = tid >> 2, pq = tid & 3;
    float4 v = *(const float4*)(A + ((long)n * H_ + h0 + hh) * 16 + pq * 4);
    unsigned short o[4] = {f2bf(v.x), f2bf(v.y), f2bf(v.z), f2bf(v.w)};
    *(uint2*)(Af2 + ((long)n * H_ + h0 + hh) * 16 + pq * 4) = *(uint2*)o;
    ld[hh][pq * 4 + 0] = v.x; ld[hh][pq * 4 + 1] = v.y;
    ld[hh][pq * 4 + 2] = v.z; ld[hh][pq * 4 + 3] = v.w;
    __syncthreads();
    if (tid < 128) {
        int p = tid >> 3, ku = tid & 7;
        int kc = (h0 >> 5) + (ku >> 2), kg = ku & 3;
        unsigned short q[8];
        #pragma unroll
        for (int e = 0; e < 8; e++) q[e] = f2bf(ld[ku * 8 + e][p]);
        *(uint4*)(AfP + ((long)(n * 32 + kc) * 64 + kg * 16 + p) * 8) = *(uint4*)q;
    }
}

// h0 = mean_p A; c0 = h0; packed h0.
__global__ void k_h0(const float* __restrict__ A, float* __restrict__ h,
                     float* __restrict__ c, unsigned short* __restrict__ hP0) {
    long id = (long)blockIdx.x * 256 + threadIdx.x;
    const float4* ap = (const float4*)(A + id * 16);
    float s = 0.f;
    #pragma unroll
    for (int q = 0; q < 4; q++) { float4 v = ap[q]; s += v.x + v.y + v.z + v.w; }
    float m = s * (1.0f / 16.0f);
    h[id] = m; c[id] = m;
    int n = (int)(id >> 10), j = (int)(id & 1023);
    hP0[((long)((n >> 4) * 32 + (j >> 5)) * 64 + ((j >> 3) & 3) * 16 + (n & 15)) * 8 + (j & 7)] = f2bf(m);
}

// t=0 score partials
__global__ __launch_bounds__(512)
void k_part0(const float* __restrict__ hbuf, const unsigned short* __restrict__ Af2,
             float* __restrict__ partial0) {
    int n = blockIdx.x;
    int tid = threadIdx.x;
    int jh = tid * 2;
    float sp[16];
    #pragma unroll
    for (int p = 0; p < 16; p++) sp[p] = 0.f;
    #pragma unroll
    for (int u = 0; u < 2; u++) {
        float hv = hbuf[(long)n * H_ + jh + u];
        const unsigned short* afp = Af2 + ((long)n * H_ + jh + u) * 16;
        bf16x8 a0 = *(const bf16x8*)(afp);
        bf16x8 a1 = *(const bf16x8*)(afp + 8);
        #pragma unroll
        for (int p = 0; p < 8; p++) { sp[p] += hv * bf2f((unsigned short)a0[p]);
                                      sp[8+p] += hv * bf2f((unsigned short)a1[p]); }
    }
    #pragma unroll
    for (int off = 1; off < 8; off <<= 1) {
        #pragma unroll
        for (int p = 0; p < 16; p++) sp[p] += __shfl_xor(sp[p], off);
    }
    int jt = tid >> 3;
    if ((tid & 7) == 0) {
        #pragma unroll
        for (int p = 0; p < 16; p++)
            partial0[((long)n * 16 + p) * 64 + jt] = sp[p];
    }
}

// reduce partial -> softmax -> w  (per-step, proven)
__global__ __launch_bounds__(64)
void k_score_tiny(const float* __restrict__ partial, float* __restrict__ wbuf) {
    int n = blockIdx.x;
    int lane = threadIdx.x;
    int p = lane & 15, c4 = lane >> 4;
    const float* src = partial + ((long)n * 16 + p) * 64 + c4 * 16;
    float s = 0.f;
    #pragma unroll
    for (int q = 0; q < 16; q++) s += src[q];
    s += __shfl_xor(s, 16);
    s += __shfl_xor(s, 32);
    s *= (1.0f / 32.0f);
    float m = s;
    #pragma unroll
    for (int off = 1; off < 16; off <<= 1) m = fmaxf(m, __shfl_xor(m, off));
    float e = expf(s - m);
    float sum = e;
    #pragma unroll
    for (int off = 1; off < 16; off <<= 1) sum += __shfl_xor(sum, off);
    if (c4 == 0) wbuf[n * 16 + p] = e / sum;
}

// AW = AfP @ WattnP^T (R10-proven, untouched)
__global__ __launch_bounds__(256, 2)
void k_aw(const unsigned short* __restrict__ AfP, const unsigned short* __restrict__ WattnP,
          unsigned short* __restrict__ AW) {
    int tid = threadIdx.x;
    int wv = tid >> 6, lane = tid & 63;
    int wr = wv >> 1, wc = wv & 1;
    int cl = lane & 15, kg = lane >> 4;
    int at0 = blockIdx.x * 8 + wr * 4;
    int jt0 = blockIdx.y * 8 + wc * 4;

    f32x4 acc[4][4];
    #pragma unroll
    for (int i = 0; i < 4; i++)
        #pragma unroll
        for (int j = 0; j < 4; j++) acc[i][j] = (f32x4){0.f, 0.f, 0.f, 0.f};

    const unsigned short* apx[4];
    const unsigned short* bpx[4];
    #pragma unroll
    for (int i = 0; i < 4; i++) {
        apx[i] = AfP    + (long)(at0 + i) * (32 * 512) + lane * 8;
        bpx[i] = WattnP + (long)(jt0 + i) * (32 * 512) + lane * 8;
    }
    #pragma unroll 2
    for (int kc = 0; kc < 32; kc++) {
        bf16x8 a[4], b[4];
        #pragma unroll
        for (int i = 0; i < 4; i++) a[i] = *(const bf16x8*)(apx[i] + kc * 512);
        #pragma unroll
        for (int i = 0; i < 4; i++) b[i] = *(const bf16x8*)(bpx[i] + kc * 512);
        #pragma unroll
        for (int i = 0; i < 4; i++)
            #pragma unroll
            for (int j = 0; j < 4; j++)
                acc[i][j] = __builtin_amdgcn_mfma_f32_16x16x32_bf16(a[i], b[j], acc[i][j], 0, 0, 0);
    }
    #pragma unroll
    for (int i = 0; i < 4; i++) {
        int n = at0 + i;
        #pragma unroll
        for (int j = 0; j < 4; j++) {
            int jj = (jt0 + j) * 16 + cl;
            #pragma unroll
            for (int v = 0; v < 4; v++) {
                int p = kg * 4 + v;
                AW[((long)n * G4_ + jj) * 16 + p] = f2bf(acc[i][j][v]);
            }
        }
    }
}

// actx = xP @ WxP^T (k_aw clone, M=8192). actx bf16 [8192 m][4096 j],
// m row = tile*16 + (n&15) matching xP tile = t*8 + (n>>4).
__global__ __launch_bounds__(256, 2)
void k_actx(const unsigned short* __restrict__ xP, const unsigned short* __restrict__ WxP,
            unsigned short* __restrict__ actx) {
    int tid = threadIdx.x;
    int wv = tid >> 6, lane = tid & 63;
    int wr = wv >> 1, wc = wv & 1;
    int cl = lane & 15, kg = lane >> 4;
    int at0 = blockIdx.x * 8 + wr * 4;    // A tiles (0..511)
    int jt0 = blockIdx.y * 8 + wc * 4;    // B tiles (0..255)

    f32x4 acc[4][4];
    #pragma unroll
    for (int i = 0; i < 4; i++)
        #pragma unroll
        for (int j = 0; j < 4; j++) acc[i][j] = (f32x4){0.f, 0.f, 0.f, 0.f};

    const unsigned short* apx[4];
    const unsigned short* bpx[4];
    #pragma unroll
    for (int i = 0; i < 4; i++) {
        apx[i] = xP  + (long)(at0 + i) * (32 * 512) + lane * 8;
        bpx[i] = WxP + (long)(jt0 + i) * (32 * 512) + lane * 8;
    }
    #pragma unroll 2
    for (int kc = 0; kc < 32; kc++) {
        bf16x8 a[4], b[4];
        #pragma unroll
        for (int i = 0; i < 4; i++) a[i] = *(const bf16x8*)(apx[i] + kc * 512);
        #pragma unroll
        for (int i = 0; i < 4; i++) b[i] = *(const bf16x8*)(bpx[i] + kc * 512);
        #pragma unroll
        for (int i = 0; i < 4; i++)
            #pragma unroll
            for (int j = 0; j < 4; j++)
                acc[i][j] = __builtin_amdgcn_mfma_f32_16x16x32_bf16(a[i], b[j], acc[i][j], 0, 0, 0);
    }
    #pragma unroll
    for (int i = 0; i < 4; i++) {
        long mrow = (long)(at0 + i) * 16;
        #pragma unroll
        for (int j = 0; j < 4; j++) {
            int jj = (jt0 + j) * 16 + cl;
            #pragma unroll
            for (int v = 0; v < 4; v++)
                actx[(mrow + kg * 4 + v) * G4_ + jj] = f2bf(acc[i][j][v]);
        }
    }
}

// ------------------------------------------------------------- per step ----

// k_step: K=1024 h-only GEMM + actx/AW epilogue.
// grid (64 jt, 4 nt2), 512 thr = 8 waves (ks:4 K-quarters x rh:2 row halves).
// B fragments L1-shared across rh waves; per-step L2 traffic ~60MB (was 164).
__global__ __launch_bounds__(512, 2)
void k_step(const unsigned short* __restrict__ actx,   // bf16 [8192][4096]
            const unsigned short* __restrict__ hPin,   // packed [8 nt][32 kc][64][8]
            unsigned short* __restrict__ hPout,
            const unsigned short* __restrict__ WhP,    // [256 jti][32 kc][64][8]
            const unsigned short* __restrict__ AW,     // [N][4096][16]
            const unsigned short* __restrict__ Af2,    // [N][H][16]
            const float* __restrict__ wbuf,            // [N][16]
            const float* __restrict__ bvec,
            float* __restrict__ c,
            float* __restrict__ partOUT,               // [N][16][64]
            float* __restrict__ out, int t) {
    int tid = threadIdx.x;
    int wv = tid >> 6, lane = tid & 63;
    int ks = wv & 3, rh = wv >> 2;
    int cl = lane & 15, kg = lane >> 4;
    int jt = blockIdx.x;
    int nt2 = blockIdx.y;
    int colbase = jt * 16;

    // ---- GEMM: 16 rows (rh half) x 16 jh x 4 gates over K=256 (8 kc) ----
    f32x4 acc[4];
    #pragma unroll
    for (int g = 0; g < 4; g++) acc[g] = (f32x4){0.f, 0.f, 0.f, 0.f};

    const unsigned short* abase = hPin + ((long)(nt2 * 2 + rh) * 32 + ks * 8) * 512 + lane * 8;
    const unsigned short* bb[4];
    #pragma unroll
    for (int g = 0; g < 4; g++)
        bb[g] = WhP + ((long)(g * 64 + jt) * 32 + ks * 8) * 512 + lane * 8;

    #pragma unroll
    for (int i = 0; i < 8; i++) {
        bf16x8 a = *(const bf16x8*)(abase + i * 512);
        #pragma unroll
        for (int g = 0; g < 4; g++) {
            bf16x8 b = *(const bf16x8*)(bb[g] + i * 512);
            acc[g] = __builtin_amdgcn_mfma_f32_16x16x32_bf16(a, b, acc[g], 0, 0, 0);
        }
    }

    // ---- 4-way K reduce per rh ----
    __shared__ float red[3][2][64][17];
    __shared__ float act[4][32][17];
    if (ks != 0) {
        #pragma unroll
        for (int g = 0; g < 4; g++)
            #pragma unroll
            for (int v = 0; v < 4; v++) red[ks - 1][rh][lane][g * 4 + v] = acc[g][v];
    }
    __syncthreads();
    if (ks == 0) {
        #pragma unroll
        for (int g = 0; g < 4; g++)
            #pragma unroll
            for (int v = 0; v < 4; v++) {
                float s = acc[g][v] + red[0][rh][lane][g*4+v] + red[1][rh][lane][g*4+v]
                        + red[2][rh][lane][g*4+v];
                act[g][rh * 16 + kg * 4 + v][cl] = s;   // C/D row = 4*kg + v
            }
    }
    __syncthreads();

    // ---- epilogue: 512 thr x 1 (n, jh) cell ----
    int nloc = tid >> 4, jl = tid & 15;
    int n = nt2 * 32 + nloc, jh = colbase + jl;
    float wv16[16];
    #pragma unroll
    for (int p = 0; p < 16; p++) wv16[p] = wbuf[n * 16 + p];

    long rm = (long)(t * 8 + (n >> 4)) * 16 + (n & 15);   // actx row
    float s4[4];
    #pragma unroll
    for (int g = 0; g < 4; g++) {
        int j = g * 1024 + jh;
        const unsigned short* awp = AW + ((long)n * G4_ + j) * 16;
        bf16x8 aw0 = *(const bf16x8*)(awp);
        bf16x8 aw1 = *(const bf16x8*)(awp + 8);
        float at = 0.f;
        #pragma unroll
        for (int p = 0; p < 8; p++) at += wv16[p]     * bf2f((unsigned short)aw0[p]);
        #pragma unroll
        for (int p = 0; p < 8; p++) at += wv16[8 + p] * bf2f((unsigned short)aw1[p]);
        s4[g] = act[g][nloc][jl] + bf2f(actx[rm * G4_ + j]) + at + bvec[j];
    }
    float ig = 1.f / (1.f + expf(-s4[0]));
    float fg = 1.f / (1.f + expf(-s4[1]));
    float og = 1.f / (1.f + expf(-s4[2]));
    float gg = tanhf(s4[3]);
    long idx = (long)n * H_ + jh;
    float cn = fg * c[idx] + ig * gg;
    float hn = og * tanhf(cn);
    c[idx] = cn;
    out[((long)n * T_ + t) * H_ + jh] = hn;
    hPout[((long)((n >> 4) * 32 + (jh >> 5)) * 64 + ((jh >> 3) & 3) * 16 + (n & 15)) * 8 + (jh & 7)] = f2bf(hn);

    // score partials for t+1
    const unsigned short* afp = Af2 + ((long)n * H_ + jh) * 16;
    bf16x8 af0 = *(const bf16x8*)(afp);
    bf16x8 af1 = *(const bf16x8*)(afp + 8);
    float sp[16];
    #pragma unroll
    for (int p = 0; p < 8; p++) { sp[p]     = hn * bf2f((unsigned short)af0[p]);
                                  sp[8 + p] = hn * bf2f((unsigned short)af1[p]); }
    #pragma unroll
    for (int off = 1; off < 16; off <<= 1) {
        #pragma unroll
        for (int p = 0; p < 16; p++) sp[p] += __shfl_xor(sp[p], off);
    }
    float outv = 0.f;
    #pragma unroll
    for (int p = 0; p < 16; p++) if (jl == p) outv = sp[p];
    partOUT[((long)n * 16 + jl) * 64 + jt] = outv;
}

// ---------------------------------------------------------------- launch ----

extern "C" void kernel_launch(void* const* d_in, const int* in_sizes, int n_in,
                              void* d_out, int out_size, void* d_ws, size_t ws_size,
                              hipStream_t stream) {
    const float* x     = (const float*)d_in[0];
    const float* A     = (const float*)d_in[1];
    const float* Wx    = (const float*)d_in[2];
    const float* Wh    = (const float*)d_in[3];
    const float* Wattn = (const float*)d_in[4];
    const float* b     = (const float*)d_in[5];
    float* out = (float*)d_out;

    char* ws = (char*)d_ws;
    size_t off = 0;
    auto alloc = [&](size_t bytes) -> void* {
        void* p = ws + off;
        off += (bytes + 255) & ~(size_t)255;
        return p;
    };
    unsigned short* xP     = (unsigned short*)alloc((size_t)512 * 32 * 512 * 2);   // 16.8MB
    unsigned short* WxP    = (unsigned short*)alloc((size_t)256 * 32 * 512 * 2);   // 8.4MB
    unsigned short* WhP    = (unsigned short*)alloc((size_t)256 * 32 * 512 * 2);   // 8.4MB
    unsigned short* WattnP = (unsigned short*)alloc((size_t)256 * 32 * 512 * 2);   // 8.4MB
    unsigned short* AfP    = (unsigned short*)alloc((size_t)128 * 32 * 512 * 2);   // 4.2MB
    unsigned short* Af2    = (unsigned short*)alloc((size_t)N_ * H_ * 16 * 2);     // 4.2MB
    unsigned short* AW     = (unsigned short*)alloc((size_t)N_ * G4_ * 16 * 2);    // 16.8MB
    unsigned short* actx   = (unsigned short*)alloc((size_t)8192 * G4_ * 2);       // 67.1MB
    float*          hbuf   = (float*)alloc((size_t)N_ * H_ * 4);
    float*          cbuf   = (float*)alloc((size_t)N_ * H_ * 4);
    unsigned short* hP0    = (unsigned short*)alloc((size_t)8 * 32 * 512 * 2);
    unsigned short* hP1    = (unsigned short*)alloc((size_t)8 * 32 * 512 * 2);
    float*          part0  = (float*)alloc((size_t)N_ * 16 * 64 * 4);
    float*          part1  = (float*)alloc((size_t)N_ * 16 * 64 * 4);
    float*          wbuf   = (float*)alloc((size_t)N_ * 16 * 4);

    // prep
    k_pack_w<<<dim3(128, 16), dim3(256), 0, stream>>>(Wx,    WxP,    0, 32);
    k_pack_w<<<dim3(128, 16), dim3(256), 0, stream>>>(Wh,    WhP,    0, 32);
    k_pack_w<<<dim3(128, 16), dim3(256), 0, stream>>>(Wattn, WattnP, 0, 32);
    k_pack_x2<<<dim3(4096), dim3(256), 0, stream>>>(x, xP);
    k_pack_af<<<dim3(128, 16), dim3(256), 0, stream>>>(A, AfP, Af2);
    k_h0<<<dim3(512), dim3(256), 0, stream>>>(A, hbuf, cbuf, hP0);
    k_part0<<<dim3(N_), dim3(512), 0, stream>>>(hbuf, Af2, part0);
    k_aw<<<dim3(16, 32), dim3(256), 0, stream>>>(AfP, WattnP, AW);
    k_actx<<<dim3(64, 32), dim3(256), 0, stream>>>(xP, WxP, actx);

    // recurrence
    for (int t = 0; t < T_; t++) {
        unsigned short* hin  = (t & 1) ? hP1 : hP0;
        unsigned short* hout = (t & 1) ? hP0 : hP1;
        float* pIN  = (t & 1) ? part1 : part0;
        float* pOUT = (t & 1) ? part0 : part1;
        k_score_tiny<<<dim3(N_), dim3(64), 0, stream>>>(pIN, wbuf);
        k_step<<<dim3(64, 4), dim3(512), 0, stream>>>(actx, hin, hout, WhP, AW, Af2,
                                                      wbuf, b, cbuf, pOUT, out, t);
    }
}